// Round 8
// baseline (717.332 us; speedup 1.0000x reference)
//
#include <hip/hip_runtime.h>
#include <hip/hip_fp16.h>

#define B_ 256
#define T_ 200
#define H_ 256
#define G3 768            // 3*H
#define NV 50001          // V+1

typedef _Float16 half2v __attribute__((ext_vector_type(2)));
typedef _Float16 half4v __attribute__((ext_vector_type(4)));
typedef _Float16 half8v __attribute__((ext_vector_type(8)));
typedef float f32x4 __attribute__((ext_vector_type(4)));

union U32H2 { unsigned int u; half2v h; };

__device__ __forceinline__ float sigmoidf_(float x) {
  return 1.f / (1.f + __expf(-x));
}
__device__ __forceinline__ float tanhf_(float x) {
  float ax = fabsf(x);
  float e = __expf(-2.f * ax);
  float t = (1.f - e) / (1.f + e);
  return copysignf(t, x);
}
__device__ __forceinline__ f32x4 mfma16(half8v a, half8v b, f32x4 c) {
  return __builtin_amdgcn_mfma_f32_16x16x32_f16(a, b, c, 0, 0, 0);
}

// ---- pack w_hh [256][768] fp32 -> wave-major MFMA B-fragment fp16.
// Frag (w, kc, p): nt = (p>>1)*16 + w*2 + (p&1); B[lane][j] =
// w_hh[kc*32 + (lane>>4)*8 + j][nt*16 + (lane&15)].
// uint index = ((w*48 + kc*6 + p)*64 + lane)*4 + jp  (halfs 2jp,2jp+1).
// Each wave's 48 fragments are contiguous -> cheap stream addressing.
__global__ __launch_bounds__(256) void pack_whh_wv(
    const float* __restrict__ whh, unsigned int* __restrict__ out) {
  int idx = blockIdx.x * 256 + threadIdx.x;   // 0..98303
  int jp = idx & 3;
  int l = (idx >> 2) & 63;
  int rest = idx >> 8;        // w*48 + kc*6 + p
  int p = rest % 6;
  int rest2 = rest / 6;       // w*8 + kc
  int kc = rest2 & 7;
  int w = rest2 >> 3;
  int nt = (p >> 1) * 16 + w * 2 + (p & 1);
  int col = nt * 16 + (l & 15);
  int k = kc * 32 + (l >> 4) * 8 + jp * 2;
  U32H2 u;
  u.h.x = (_Float16)whh[(size_t)k * G3 + col];
  u.h.y = (_Float16)whh[(size_t)(k + 1) * G3 + col];
  out[idx] = u.u;
}

// ---- pack w_ih -> transposed fp16 [768 cols][256 k] (gates_mfma B staging).
__global__ __launch_bounds__(256) void pack_wiht(
    const float* __restrict__ wih, unsigned int* __restrict__ out) {
  int idx = blockIdx.x * 256 + threadIdx.x;   // 0..98303
  int col = idx >> 7;
  int kk = (idx & 127) * 2;
  U32H2 u;
  u.h.x = (_Float16)wih[(size_t)kk * G3 + col];
  u.h.y = (_Float16)wih[(size_t)(kk + 1) * G3 + col];
  out[idx] = u.u;
}

// ---- K1: gates = emb[ids] @ w_ih + b_ih via f16 MFMA (round-2, measured).
__global__ __launch_bounds__(512) void gates_mfma(
    const int* __restrict__ ids, const float* __restrict__ emb,
    const __half* __restrict__ wih_t, const float* __restrict__ b_ih,
    __half* __restrict__ gates) {
  __shared__ __align__(16) _Float16 As[128 * 72];   // [row][k] stride 72
  __shared__ __align__(16) _Float16 Bs[256 * 72];   // [col][k] stride 72
  __shared__ int ids_s[128];
  __shared__ float bs[256];
  const int tid = threadIdx.x;
  const int r0 = blockIdx.x * 128;
  const int c0 = blockIdx.y * 256;
  const int w = tid >> 6, lane = tid & 63;
  const int wm = w >> 2, wn = w & 3;
  const int lr = lane & 15, lk = lane >> 4;

  if (tid < 128) ids_s[tid] = ids[r0 + tid];
  if (tid < 256) bs[tid] = b_ih[c0 + tid];
  __syncthreads();

  f32x4 acc[4][4];
#pragma unroll
  for (int i = 0; i < 4; ++i)
#pragma unroll
    for (int j = 0; j < 4; ++j) acc[i][j] = (f32x4){0.f, 0.f, 0.f, 0.f};

  for (int c = 0; c < 4; ++c) {
    const int kc = c * 64;
#pragma unroll
    for (int r4 = 0; r4 < 4; ++r4) {
      int q = tid + r4 * 512;
      int row = q >> 4;
      int kk = (q & 15) * 4;
      const float4 v = *(const float4*)&emb[(size_t)ids_s[row] * H_ + kc + kk];
      half4v hv = {(_Float16)v.x, (_Float16)v.y, (_Float16)v.z, (_Float16)v.w};
      *(half4v*)&As[row * 72 + kk] = hv;
    }
#pragma unroll
    for (int r4 = 0; r4 < 4; ++r4) {
      int q = tid + r4 * 512;
      int col = q >> 3;
      int cc = q & 7;
      uint4 v = *(const uint4*)((const unsigned short*)wih_t +
                                (size_t)(c0 + col) * H_ + kc + cc * 8);
      *(uint4*)&Bs[col * 72 + cc * 8] = v;
    }
    __syncthreads();
#pragma unroll
    for (int ks = 0; ks < 2; ++ks) {
      half8v af[4], bf[4];
#pragma unroll
      for (int i = 0; i < 4; ++i)
        af[i] = *(const half8v*)&As[(wm * 64 + i * 16 + lr) * 72 + ks * 32 + lk * 8];
#pragma unroll
      for (int j = 0; j < 4; ++j)
        bf[j] = *(const half8v*)&Bs[(wn * 64 + j * 16 + lr) * 72 + ks * 32 + lk * 8];
#pragma unroll
      for (int i = 0; i < 4; ++i)
#pragma unroll
        for (int j = 0; j < 4; ++j)
          acc[i][j] = mfma16(af[i], bf[j], acc[i][j]);
    }
    __syncthreads();
  }
#pragma unroll
  for (int j = 0; j < 4; ++j) {
    const int col = c0 + wn * 64 + j * 16 + lr;
    const float bj = bs[wn * 64 + j * 16 + lr];
#pragma unroll
    for (int i = 0; i < 4; ++i) {
      const int row = r0 + wm * 64 + i * 16 + lk * 4;
#pragma unroll
      for (int r = 0; r < 4; ++r)
        gates[(size_t)(row + r) * G3 + col] = (__half)(acc[i][j][r] + bj);
    }
  }
}

// ---- K2: cross-step-pipelined M=1 MFMA GRU recurrence. 256 WGs x 512 thr.
// kc 0..2 resident in LDS (147 KB, DS pipe ~85 B/cy). kc 3..7 in persistent
// rotation registers S3..S7 (120 VGPR): consume at step t, immediately
// re-issue the (loop-invariant) load for step t+1 -> a full step (~2000 cy)
// of latency cover, VMEM runs at its 129 B/cy BW bound. Opaque asm loads
// (no LICM/remat) + hand-counted s_waitcnt vmcnt(30) (queue: 30 S + 6 gx,
// in-order retirement, oldest 6 = the phase's operands). Raw s_barrier with
// lgkmcnt-only drain keeps the stream alive across the step boundary; h is
// double-buffered in LDS so one barrier/step suffices.
__global__ __launch_bounds__(512) void rec_m1(
    const int* __restrict__ lens, const unsigned int* __restrict__ whh_w,
    const float* __restrict__ b_hh, const __half* __restrict__ gates,
    float* __restrict__ hfin) {
  __shared__ __align__(16) uint4 Wl[8 * 18 * 64];   // 147,456 B: kc 0..2
  __shared__ __align__(16) _Float16 hpk[2][256];    // double-buffered h
  const int tid = threadIdx.x;
  const int b = blockIdx.x;
  const int w = tid >> 6, lane = tid & 63;
  const int lr = lane & 15, lk = lane >> 4;

  const uint4* wf = (const uint4*)whh_w;
  const uint4* wfw = wf + (size_t)w * (48 * 64) + lane;   // this wave's frags

  // persistent cross-step stream buffers (opaque loads)
  uint4 S3[6], S4[6], S5[6], S6[6], S7[6];
#define LOADS(S, KC)                                                     \
  _Pragma("unroll") for (int p = 0; p < 6; ++p) {                        \
    asm volatile("global_load_dwordx4 %0, %1, off"                       \
                 : "=v"(S[p])                                            \
                 : "v"(wfw + (KC * 6 + p) * 64));                        \
  }
  LOADS(S3, 3) LOADS(S4, 4) LOADS(S5, 5) LOADS(S6, 6) LOADS(S7, 7)

  // stage kc 0..2 (18 frags x 8 waves) into LDS, coalesced
#pragma unroll
  for (int i = 0; i < 18; ++i) {
    int d = tid + i * 512;            // 0..9215
    int wv = d / 1152;                // 18*64
    int r = d - wv * 1152;
    Wl[d] = wf[(size_t)wv * (48 * 64) + r];
  }
  if (tid < 256) ((unsigned int*)hpk)[tid] = 0;   // zero both h buffers

  const int len = lens[b];
  float bhh[6];
  int gcol[6];
#pragma unroll
  for (int p = 0; p < 6; ++p) {
    int col = (p >> 1) * 256 + w * 32 + (p & 1) * 16 + lr;
    bhh[p] = b_hh[col];
    gcol[p] = col;
  }
  float h0 = 0.f, h1 = 0.f;
  __syncthreads();   // drains prologue (incl. asm loads) + staging

  const uint4* WlW = Wl + w * 1152;
  const __half* gb = gates + (size_t)b * T_ * G3;

  for (int t = 0; t < len; ++t) {
    const _Float16* hp = hpk[t & 1];
    float gx[6];
    if (lane < 16) {
      const __half* gt = gb + (size_t)t * G3;
#pragma unroll
      for (int p = 0; p < 6; ++p) gx[p] = (float)gt[gcol[p]];
    }
    f32x4 acc[6];
#pragma unroll
    for (int p = 0; p < 6; ++p) acc[p] = (f32x4){0.f, 0.f, 0.f, 0.f};

    // kc 0..2 from LDS (h A-fragment is a broadcast b128 read)
#pragma unroll
    for (int kc = 0; kc < 3; ++kc) {
      half8v a = *(const half8v*)&hp[kc * 32 + lk * 8];
#pragma unroll
      for (int p = 0; p < 6; ++p)
        acc[p] = mfma16(
            a, __builtin_bit_cast(half8v, WlW[(kc * 6 + p) * 64 + lane]),
            acc[p]);
    }
    // streamed kc 3..7: wait oldest-6 -> consume regs -> re-issue for t+1
#define PHASE(S, KC)                                                     \
    {                                                                    \
      asm volatile("s_waitcnt vmcnt(30)");                               \
      __builtin_amdgcn_sched_barrier(0);                                 \
      half8v a = *(const half8v*)&hp[KC * 32 + lk * 8];                  \
      _Pragma("unroll") for (int p = 0; p < 6; ++p)                      \
          acc[p] = mfma16(a, __builtin_bit_cast(half8v, S[p]), acc[p]);  \
      _Pragma("unroll") for (int p = 0; p < 6; ++p) {                    \
        asm volatile("global_load_dwordx4 %0, %1, off"                   \
                     : "=v"(S[p])                                        \
                     : "v"(wfw + (KC * 6 + p) * 64));                    \
      }                                                                  \
    }
    PHASE(S3, 3) PHASE(S4, 4) PHASE(S5, 5) PHASE(S6, 6) PHASE(S7, 7)
#undef PHASE

    // in-register GRU update (every acc reg holds rec[col]; use reg 0)
    if (lane < 16) {
      float z0 = sigmoidf_(gx[0] + acc[0][0] + bhh[0]);
      float z1 = sigmoidf_(gx[1] + acc[1][0] + bhh[1]);
      float r0 = sigmoidf_(gx[2] + acc[2][0] + bhh[2]);
      float r1 = sigmoidf_(gx[3] + acc[3][0] + bhh[3]);
      float q0 = tanhf_(gx[4] + r0 * (acc[4][0] + bhh[4]));
      float q1 = tanhf_(gx[5] + r1 * (acc[5][0] + bhh[5]));
      h0 = z0 * h0 + (1.f - z0) * q0;
      h1 = z1 * h1 + (1.f - z1) * q1;
      _Float16* hn = hpk[(t + 1) & 1];
      hn[w * 32 + lr] = (_Float16)h0;
      hn[w * 32 + 16 + lr] = (_Float16)h1;
    }
    // raw barrier: drain LDS only; the 30 stream loads stay in flight
    __builtin_amdgcn_sched_barrier(0);
    asm volatile("s_waitcnt lgkmcnt(0)");
    __builtin_amdgcn_sched_barrier(0);
    __builtin_amdgcn_s_barrier();
    __builtin_amdgcn_sched_barrier(0);
  }
  asm volatile("s_waitcnt vmcnt(0)");   // drain asm loads before endpgm
  if (lane < 16) {
    hfin[(size_t)b * H_ + w * 32 + lr] = h0;
    hfin[(size_t)b * H_ + w * 32 + 16 + lr] = h1;
  }
}

// ---- K3: logits = hfin @ emb^T via hi/lo-split f16 MFMA (round-2, measured).
__global__ __launch_bounds__(512) void logits_mfma(
    const float* __restrict__ hfin, const float* __restrict__ emb,
    float* __restrict__ out) {
  __shared__ __align__(16) _Float16 As[256 * 72];
  __shared__ __align__(16) _Float16 Bs[64 * 72];
  const int tid = threadIdx.x;
  const int n0 = blockIdx.x * 64;
  const int w = tid >> 6, lane = tid & 63;
  const int wm = w >> 1, wn = w & 1;
  const int lr = lane & 15, lk = lane >> 4;

  f32x4 a1[4][2], a2[4][2];
#pragma unroll
  for (int i = 0; i < 4; ++i)
#pragma unroll
    for (int j = 0; j < 2; ++j) {
      a1[i][j] = (f32x4){0.f, 0.f, 0.f, 0.f};
      a2[i][j] = (f32x4){0.f, 0.f, 0.f, 0.f};
    }

  for (int c = 0; c < 8; ++c) {
    const int kc = c * 32;
#pragma unroll
    for (int r4 = 0; r4 < 4; ++r4) {
      int q = tid + r4 * 512;
      int row = q >> 3;
      int kk = (q & 7) * 4;
      float4 v = *(const float4*)&hfin[(size_t)row * H_ + kc + kk];
      half4v hi = {(_Float16)v.x, (_Float16)v.y, (_Float16)v.z, (_Float16)v.w};
      half4v lo = {(_Float16)((v.x - (float)hi.x) * 1024.f),
                   (_Float16)((v.y - (float)hi.y) * 1024.f),
                   (_Float16)((v.z - (float)hi.z) * 1024.f),
                   (_Float16)((v.w - (float)hi.w) * 1024.f)};
      int base = row * 72 + (kk >> 3) * 16 + (kk & 7);
      *(half4v*)&As[base] = hi;
      *(half4v*)&As[base + 8] = lo;
    }
    {
      int col = tid >> 3;
      int kk = (tid & 7) * 4;
      int n = n0 + col;
      float4 v = (n < NV) ? *(const float4*)&emb[(size_t)n * H_ + kc + kk]
                          : make_float4(0.f, 0.f, 0.f, 0.f);
      half4v hi = {(_Float16)v.x, (_Float16)v.y, (_Float16)v.z, (_Float16)v.w};
      half4v lo = {(_Float16)((v.x - (float)hi.x) * 1024.f),
                   (_Float16)((v.y - (float)hi.y) * 1024.f),
                   (_Float16)((v.z - (float)hi.z) * 1024.f),
                   (_Float16)((v.w - (float)hi.w) * 1024.f)};
      int base = col * 72 + (kk >> 3) * 16 + (kk & 7);
      *(half4v*)&Bs[base] = hi;
      *(half4v*)&Bs[base + 8] = lo;
    }
    __syncthreads();
    half8v ah[4], al[4];
#pragma unroll
    for (int i = 0; i < 4; ++i) {
      int base = (wm * 64 + i * 16 + lr) * 72 + lk * 16;
      ah[i] = *(const half8v*)&As[base];
      al[i] = *(const half8v*)&As[base + 8];
    }
#pragma unroll
    for (int j = 0; j < 2; ++j) {
      int base = (wn * 32 + j * 16 + lr) * 72 + lk * 16;
      half8v bh = *(const half8v*)&Bs[base];
      half8v bl = *(const half8v*)&Bs[base + 8];
#pragma unroll
      for (int i = 0; i < 4; ++i) {
        a1[i][j] = mfma16(ah[i], bh, a1[i][j]);
        a2[i][j] = mfma16(ah[i], bl, a2[i][j]);
        a2[i][j] = mfma16(al[i], bh, a2[i][j]);
      }
    }
    __syncthreads();
  }
#pragma unroll
  for (int j = 0; j < 2; ++j) {
    int n = n0 + wn * 32 + j * 16 + lr;
    if (n < NV) {
#pragma unroll
      for (int i = 0; i < 4; ++i) {
        int row = wm * 64 + i * 16 + lk * 4;
#pragma unroll
        for (int r = 0; r < 4; ++r)
          out[(size_t)(row + r) * NV + n] =
              a1[i][j][r] + a2[i][j][r] * (1.f / 1024.f);
      }
    }
  }
}

extern "C" void kernel_launch(void* const* d_in, const int* in_sizes, int n_in,
                              void* d_out, int out_size, void* d_ws, size_t ws_size,
                              hipStream_t stream) {
  const int* ids = (const int*)d_in[0];
  const int* lens = (const int*)d_in[1];
  const float* emb = (const float*)d_in[2];
  const float* w_ih = (const float*)d_in[3];
  const float* w_hh = (const float*)d_in[4];
  const float* b_ih = (const float*)d_in[5];
  const float* b_hh = (const float*)d_in[6];
  float* out = (float*)d_out;

  char* ws = (char*)d_ws;
  __half* gates = (__half*)ws;                           // 78,643,200 B
  float* hfin = (float*)(ws + (size_t)B_ * T_ * G3 * sizeof(__half));
  unsigned int* whh_w =
      (unsigned int*)(ws + (size_t)B_ * T_ * G3 * sizeof(__half)
                      + (size_t)B_ * H_ * sizeof(float));   // 393,216 B
  unsigned int* wih_t = whh_w + (size_t)98304;              // 393,216 B

  pack_whh_wv<<<dim3(384), dim3(256), 0, stream>>>(w_hh, whh_w);
  pack_wiht<<<dim3(384), dim3(256), 0, stream>>>(w_ih, wih_t);
  gates_mfma<<<dim3(400, 3), dim3(512), 0, stream>>>(
      ids, emb, (const __half*)wih_t, b_ih, gates);
  rec_m1<<<dim3(B_), dim3(512), 0, stream>>>(lens, whh_w, b_hh, gates, hfin);
  logits_mfma<<<dim3((NV + 63) / 64), dim3(512), 0, stream>>>(hfin, emb, out);
}

// Round 9
// 691.576 us; speedup vs baseline: 1.0372x; 1.0372x over previous
//
#include <hip/hip_runtime.h>
#include <hip/hip_fp16.h>

#define B_ 256
#define T_ 200
#define H_ 256
#define G3 768            // 3*H
#define NV 50001          // V+1

typedef _Float16 half2v __attribute__((ext_vector_type(2)));
typedef _Float16 half4v __attribute__((ext_vector_type(4)));
typedef _Float16 half8v __attribute__((ext_vector_type(8)));
typedef float f32x4 __attribute__((ext_vector_type(4)));

union U32H2 { unsigned int u; half2v h; };
union U16H { unsigned short s; _Float16 h; };

__device__ __forceinline__ float sigmoidf_(float x) {
  return 1.f / (1.f + __expf(-x));
}
__device__ __forceinline__ float tanhf_(float x) {
  float ax = fabsf(x);
  float e = __expf(-2.f * ax);
  float t = (1.f - e) / (1.f + e);
  return copysignf(t, x);
}
__device__ __forceinline__ f32x4 mfma16(half8v a, half8v b, f32x4 c) {
  return __builtin_amdgcn_mfma_f32_16x16x32_f16(a, b, c, 0, 0, 0);
}

// ---- pack w_hh [256][768] fp32 -> 16-wave MFMA B-fragment fp16.
// Wave w owns nt = {w, 16+w, 32+w} (p=0,1,2). Frag slot s = w*24 + kc*3 + p;
// B[lane][j] = w_hh[kc*32 + (lane>>4)*8 + j][nt*16 + (lane&15)] (verified
// fragment content, rounds 3/6/7). uint idx = (s*64 + lane)*4 + jp.
__global__ __launch_bounds__(256) void pack_whh_16(
    const float* __restrict__ whh, unsigned int* __restrict__ out) {
  int idx = blockIdx.x * 256 + threadIdx.x;   // 0..98303
  int jp = idx & 3;
  int l = (idx >> 2) & 63;
  int s = idx >> 8;          // w*24 + kc*3 + p
  int p = s % 3;
  int kc = (s / 3) & 7;
  int w = s / 24;
  int nt = p * 16 + w;
  int col = nt * 16 + (l & 15);
  int k = kc * 32 + (l >> 4) * 8 + jp * 2;
  U32H2 u;
  u.h.x = (_Float16)whh[(size_t)k * G3 + col];
  u.h.y = (_Float16)whh[(size_t)(k + 1) * G3 + col];
  out[idx] = u.u;
}

// ---- pack w_ih -> transposed fp16 [768 cols][256 k] (gates_mfma B staging).
__global__ __launch_bounds__(256) void pack_wiht(
    const float* __restrict__ wih, unsigned int* __restrict__ out) {
  int idx = blockIdx.x * 256 + threadIdx.x;   // 0..98303
  int col = idx >> 7;
  int kk = (idx & 127) * 2;
  U32H2 u;
  u.h.x = (_Float16)wih[(size_t)kk * G3 + col];
  u.h.y = (_Float16)wih[(size_t)(kk + 1) * G3 + col];
  out[idx] = u.u;
}

// ---- K1: gates = emb[ids] @ w_ih + b_ih via f16 MFMA (round-2, measured).
__global__ __launch_bounds__(512) void gates_mfma(
    const int* __restrict__ ids, const float* __restrict__ emb,
    const __half* __restrict__ wih_t, const float* __restrict__ b_ih,
    __half* __restrict__ gates) {
  __shared__ __align__(16) _Float16 As[128 * 72];   // [row][k] stride 72
  __shared__ __align__(16) _Float16 Bs[256 * 72];   // [col][k] stride 72
  __shared__ int ids_s[128];
  __shared__ float bs[256];
  const int tid = threadIdx.x;
  const int r0 = blockIdx.x * 128;
  const int c0 = blockIdx.y * 256;
  const int w = tid >> 6, lane = tid & 63;
  const int wm = w >> 2, wn = w & 3;
  const int lr = lane & 15, lk = lane >> 4;

  if (tid < 128) ids_s[tid] = ids[r0 + tid];
  if (tid < 256) bs[tid] = b_ih[c0 + tid];
  __syncthreads();

  f32x4 acc[4][4];
#pragma unroll
  for (int i = 0; i < 4; ++i)
#pragma unroll
    for (int j = 0; j < 4; ++j) acc[i][j] = (f32x4){0.f, 0.f, 0.f, 0.f};

  for (int c = 0; c < 4; ++c) {
    const int kc = c * 64;
#pragma unroll
    for (int r4 = 0; r4 < 4; ++r4) {
      int q = tid + r4 * 512;
      int row = q >> 4;
      int kk = (q & 15) * 4;
      const float4 v = *(const float4*)&emb[(size_t)ids_s[row] * H_ + kc + kk];
      half4v hv = {(_Float16)v.x, (_Float16)v.y, (_Float16)v.z, (_Float16)v.w};
      *(half4v*)&As[row * 72 + kk] = hv;
    }
#pragma unroll
    for (int r4 = 0; r4 < 4; ++r4) {
      int q = tid + r4 * 512;
      int col = q >> 3;
      int cc = q & 7;
      uint4 v = *(const uint4*)((const unsigned short*)wih_t +
                                (size_t)(c0 + col) * H_ + kc + cc * 8);
      *(uint4*)&Bs[col * 72 + cc * 8] = v;
    }
    __syncthreads();
#pragma unroll
    for (int ks = 0; ks < 2; ++ks) {
      half8v af[4], bf[4];
#pragma unroll
      for (int i = 0; i < 4; ++i)
        af[i] = *(const half8v*)&As[(wm * 64 + i * 16 + lr) * 72 + ks * 32 + lk * 8];
#pragma unroll
      for (int j = 0; j < 4; ++j)
        bf[j] = *(const half8v*)&Bs[(wn * 64 + j * 16 + lr) * 72 + ks * 32 + lk * 8];
#pragma unroll
      for (int i = 0; i < 4; ++i)
#pragma unroll
        for (int j = 0; j < 4; ++j)
          acc[i][j] = mfma16(af[i], bf[j], acc[i][j]);
    }
    __syncthreads();
  }
#pragma unroll
  for (int j = 0; j < 4; ++j) {
    const int col = c0 + wn * 64 + j * 16 + lr;
    const float bj = bs[wn * 64 + j * 16 + lr];
#pragma unroll
    for (int i = 0; i < 4; ++i) {
      const int row = r0 + wm * 64 + i * 16 + lk * 4;
#pragma unroll
      for (int r = 0; r < 4; ++r)
        gates[(size_t)(row + r) * G3 + col] = (__half)(acc[i][j][r] + bj);
    }
  }
}

#define GLD4(dst, addr, IMMSTR)                                        \
  asm volatile("global_load_dwordx4 %0, %1, off offset:" IMMSTR       \
               : "=v"(dst) : "v"(addr))
#define GLDU(dst, addr, IMMSTR)                                        \
  asm volatile("global_load_ushort %0, %1, off offset:" IMMSTR        \
               : "=v"(dst) : "v"(addr))
#define SB __builtin_amdgcn_sched_barrier(0)

// ---- K2: GRU recurrence, 256 WGs x 1024 thr (16 waves, 4/SIMD -> the
// allocator's natural 128-VGPR target; no cap fight). Wave w owns the
// (z,r,h~) column triple for cols w*16..w*16+15 -> in-register GRU update.
// kc 0..1 resident in LDS (98 KB). kc 2..7 in 18 persistent uint4 stream
// regs: consume at step t, re-issue (loop-invariant addr) for t+1 -> full
// step of latency cover. ALL loop VMEM is inline-asm (incl. gate loads) so
// no compiler-emitted waits can drain the pipeline (the round-8 bug);
// hand-counted s_waitcnt vmcnt(18) per phase (queue: 18 S + 3 gx, in-order
// retirement). Raw s_barrier with lgkmcnt-only drain; h double-buffered.
__global__ __launch_bounds__(1024) void rec_m1(
    const int* __restrict__ lens, const unsigned int* __restrict__ whh_w,
    const float* __restrict__ b_hh, const __half* __restrict__ gates,
    float* __restrict__ hfin) {
  __shared__ __align__(16) uint4 Wl[96 * 64];       // 98,304 B: kc 0..1
  __shared__ __align__(16) _Float16 hpk[2][256];    // double-buffered h
  const int tid = threadIdx.x;
  const int b = blockIdx.x;
  const int w = tid >> 6, lane = tid & 63;
  const int lr = lane & 15, lk = lane >> 4;

  // stream anchors (frag f = kc*3+p at byte w*24576 + f*1024 + lane*16)
  const char* base = (const char*)whh_w + (size_t)w * 24576 + lane * 16;
  const char* A1 = base + 9216;    // f=9
  const char* A2 = base + 16384;   // f=16
  const char* A3 = base + 22528;   // f=22

  // persistent cross-step stream regs: S{kc}[p], kc 2..7 (72 VGPRs)
  uint4 S2[3], S3[3], S4[3], S5[3], S6[3], S7[3];
  GLD4(S2[0], A1, "-3072"); GLD4(S2[1], A1, "-2048"); GLD4(S2[2], A1, "-1024");
  GLD4(S3[0], A1, "0");     GLD4(S3[1], A1, "1024");  GLD4(S3[2], A1, "2048");
  GLD4(S4[0], A1, "3072");  GLD4(S4[1], A2, "-3072"); GLD4(S4[2], A2, "-2048");
  GLD4(S5[0], A2, "-1024"); GLD4(S5[1], A2, "0");     GLD4(S5[2], A2, "1024");
  GLD4(S6[0], A2, "2048");  GLD4(S6[1], A2, "3072");  GLD4(S6[2], A3, "-2048");
  GLD4(S7[0], A3, "-1024"); GLD4(S7[1], A3, "0");     GLD4(S7[2], A3, "1024");

  // stage kc 0..1 (16 waves x 6 frags) into LDS, coalesced
  const uint4* wf = (const uint4*)whh_w;
#pragma unroll
  for (int i = 0; i < 6; ++i) {
    int d = tid + i * 1024;       // 0..6143
    int s = d >> 6;               // 0..95
    int wv = s / 6;
    int r6 = s - wv * 6;
    Wl[d] = wf[(wv * 24 + r6) * 64 + (d & 63)];
  }
  if (tid < 256) ((unsigned int*)hpk)[tid] = 0;   // zero both h buffers

  const int len = lens[b];
  float bhh[3];
#pragma unroll
  for (int g = 0; g < 3; ++g) bhh[g] = b_hh[g * 256 + w * 16 + lr];
  float h = 0.f;
  const char* Gp = (const char*)gates +
                   ((size_t)b * T_ * G3 + w * 16 + lr) * 2;
  __syncthreads();   // drains prologue stream (values land) + staging

  const uint4* WlW = Wl + w * 6 * 64;

  for (int t = 0; t < len; ++t) {
    const _Float16* hp = hpk[t & 1];
    // gate inputs via asm (must not perturb vmcnt accounting)
    unsigned int gxr0, gxr1, gxr2;
    GLDU(gxr0, Gp, "0");
    GLDU(gxr1, Gp, "512");
    GLDU(gxr2, Gp, "1024");
    SB;

    f32x4 acc[3];
#pragma unroll
    for (int p = 0; p < 3; ++p) acc[p] = (f32x4){0.f, 0.f, 0.f, 0.f};

    // kc 0..1 from LDS (compiler-scheduled region, no walls)
#pragma unroll
    for (int kc = 0; kc < 2; ++kc) {
      half8v a = *(const half8v*)&hp[kc * 32 + lk * 8];
#pragma unroll
      for (int p = 0; p < 3; ++p)
        acc[p] = mfma16(
            a, __builtin_bit_cast(half8v, WlW[(kc * 3 + p) * 64 + lane]),
            acc[p]);
    }
    half8v aC = *(const half8v*)&hp[2 * 32 + lk * 8];
    half8v aN;

    // streamed phases kc 2..7: wait(18) -> 3 MFMA -> read next h frag ->
    // re-issue this phase's loads for step t+1
#define PHASE(S, NEXTKC, L0, I0, L1, I1, L2, I2)                          \
    {                                                                     \
      asm volatile("s_waitcnt vmcnt(18)");                                \
      SB;                                                                 \
      acc[0] = mfma16(aC, __builtin_bit_cast(half8v, S[0]), acc[0]);      \
      acc[1] = mfma16(aC, __builtin_bit_cast(half8v, S[1]), acc[1]);      \
      acc[2] = mfma16(aC, __builtin_bit_cast(half8v, S[2]), acc[2]);      \
      if (NEXTKC < 8) aN = *(const half8v*)&hp[NEXTKC * 32 + lk * 8];     \
      SB;                                                                 \
      GLD4(S[0], L0, I0); GLD4(S[1], L1, I1); GLD4(S[2], L2, I2);         \
      SB;                                                                 \
      aC = aN;                                                            \
    }
    PHASE(S2, 3, A1, "-3072", A1, "-2048", A1, "-1024")
    PHASE(S3, 4, A1, "0",     A1, "1024",  A1, "2048")
    PHASE(S4, 5, A1, "3072",  A2, "-3072", A2, "-2048")
    PHASE(S5, 6, A2, "-1024", A2, "0",     A2, "1024")
    PHASE(S6, 7, A2, "2048",  A2, "3072",  A3, "-2048")
    PHASE(S7, 8, A3, "-1024", A3, "0",     A3, "1024")
#undef PHASE

    // gate values landed (gx are the 3 oldest in queue)
    asm volatile("s_waitcnt vmcnt(18)");
    SB;
    U16H c0, c1, c2;
    c0.s = (unsigned short)gxr0;
    c1.s = (unsigned short)gxr1;
    c2.s = (unsigned short)gxr2;
    float z = sigmoidf_((float)c0.h + acc[0][0] + bhh[0]);
    float r = sigmoidf_((float)c1.h + acc[1][0] + bhh[1]);
    float hh = tanhf_((float)c2.h + r * (acc[2][0] + bhh[2]));
    h = z * h + (1.f - z) * hh;
    if (lane < 16) hpk[(t + 1) & 1][w * 16 + lr] = (_Float16)h;
    // raw barrier: drain LDS only; the 18 stream loads stay in flight
    SB;
    asm volatile("s_waitcnt lgkmcnt(0)");
    SB;
    __builtin_amdgcn_s_barrier();
    SB;
    Gp += 1536;   // next timestep's gate row
  }
  asm volatile("s_waitcnt vmcnt(0)");   // drain asm loads before stores/end
  if (lane < 16) hfin[(size_t)b * H_ + w * 16 + lr] = h;
}

#undef GLD4
#undef GLDU
#undef SB

// ---- K3: logits = hfin @ emb^T via hi/lo-split f16 MFMA (round-2, measured).
__global__ __launch_bounds__(512) void logits_mfma(
    const float* __restrict__ hfin, const float* __restrict__ emb,
    float* __restrict__ out) {
  __shared__ __align__(16) _Float16 As[256 * 72];
  __shared__ __align__(16) _Float16 Bs[64 * 72];
  const int tid = threadIdx.x;
  const int n0 = blockIdx.x * 64;
  const int w = tid >> 6, lane = tid & 63;
  const int wm = w >> 1, wn = w & 1;
  const int lr = lane & 15, lk = lane >> 4;

  f32x4 a1[4][2], a2[4][2];
#pragma unroll
  for (int i = 0; i < 4; ++i)
#pragma unroll
    for (int j = 0; j < 2; ++j) {
      a1[i][j] = (f32x4){0.f, 0.f, 0.f, 0.f};
      a2[i][j] = (f32x4){0.f, 0.f, 0.f, 0.f};
    }

  for (int c = 0; c < 8; ++c) {
    const int kc = c * 32;
#pragma unroll
    for (int r4 = 0; r4 < 4; ++r4) {
      int q = tid + r4 * 512;
      int row = q >> 3;
      int kk = (q & 7) * 4;
      float4 v = *(const float4*)&hfin[(size_t)row * H_ + kc + kk];
      half4v hi = {(_Float16)v.x, (_Float16)v.y, (_Float16)v.z, (_Float16)v.w};
      half4v lo = {(_Float16)((v.x - (float)hi.x) * 1024.f),
                   (_Float16)((v.y - (float)hi.y) * 1024.f),
                   (_Float16)((v.z - (float)hi.z) * 1024.f),
                   (_Float16)((v.w - (float)hi.w) * 1024.f)};
      int base = row * 72 + (kk >> 3) * 16 + (kk & 7);
      *(half4v*)&As[base] = hi;
      *(half4v*)&As[base + 8] = lo;
    }
    {
      int col = tid >> 3;
      int kk = (tid & 7) * 4;
      int n = n0 + col;
      float4 v = (n < NV) ? *(const float4*)&emb[(size_t)n * H_ + kc + kk]
                          : make_float4(0.f, 0.f, 0.f, 0.f);
      half4v hi = {(_Float16)v.x, (_Float16)v.y, (_Float16)v.z, (_Float16)v.w};
      half4v lo = {(_Float16)((v.x - (float)hi.x) * 1024.f),
                   (_Float16)((v.y - (float)hi.y) * 1024.f),
                   (_Float16)((v.z - (float)hi.z) * 1024.f),
                   (_Float16)((v.w - (float)hi.w) * 1024.f)};
      int base = col * 72 + (kk >> 3) * 16 + (kk & 7);
      *(half4v*)&Bs[base] = hi;
      *(half4v*)&Bs[base + 8] = lo;
    }
    __syncthreads();
    half8v ah[4], al[4];
#pragma unroll
    for (int i = 0; i < 4; ++i) {
      int base = (wm * 64 + i * 16 + lr) * 72 + lk * 16;
      ah[i] = *(const half8v*)&As[base];
      al[i] = *(const half8v*)&As[base + 8];
    }
#pragma unroll
    for (int j = 0; j < 2; ++j) {
      int base = (wn * 32 + j * 16 + lr) * 72 + lk * 16;
      half8v bh = *(const half8v*)&Bs[base];
      half8v bl = *(const half8v*)&Bs[base + 8];
#pragma unroll
      for (int i = 0; i < 4; ++i) {
        a1[i][j] = mfma16(ah[i], bh, a1[i][j]);
        a2[i][j] = mfma16(ah[i], bl, a2[i][j]);
        a2[i][j] = mfma16(al[i], bh, a2[i][j]);
      }
    }
    __syncthreads();
  }
#pragma unroll
  for (int j = 0; j < 2; ++j) {
    int n = n0 + wn * 32 + j * 16 + lr;
    if (n < NV) {
#pragma unroll
      for (int i = 0; i < 4; ++i) {
        int row = wm * 64 + i * 16 + lk * 4;
#pragma unroll
        for (int r = 0; r < 4; ++r)
          out[(size_t)(row + r) * NV + n] =
              a1[i][j][r] + a2[i][j][r] * (1.f / 1024.f);
      }
    }
  }
}

extern "C" void kernel_launch(void* const* d_in, const int* in_sizes, int n_in,
                              void* d_out, int out_size, void* d_ws, size_t ws_size,
                              hipStream_t stream) {
  const int* ids = (const int*)d_in[0];
  const int* lens = (const int*)d_in[1];
  const float* emb = (const float*)d_in[2];
  const float* w_ih = (const float*)d_in[3];
  const float* w_hh = (const float*)d_in[4];
  const float* b_ih = (const float*)d_in[5];
  const float* b_hh = (const float*)d_in[6];
  float* out = (float*)d_out;

  char* ws = (char*)d_ws;
  __half* gates = (__half*)ws;                           // 78,643,200 B
  float* hfin = (float*)(ws + (size_t)B_ * T_ * G3 * sizeof(__half));
  unsigned int* whh_w =
      (unsigned int*)(ws + (size_t)B_ * T_ * G3 * sizeof(__half)
                      + (size_t)B_ * H_ * sizeof(float));   // 393,216 B
  unsigned int* wih_t = whh_w + (size_t)98304;              // 393,216 B

  pack_whh_16<<<dim3(384), dim3(256), 0, stream>>>(w_hh, whh_w);
  pack_wiht<<<dim3(384), dim3(256), 0, stream>>>(w_ih, wih_t);
  gates_mfma<<<dim3(400, 3), dim3(512), 0, stream>>>(
      ids, emb, (const __half*)wih_t, b_ih, gates);
  rec_m1<<<dim3(B_), dim3(1024), 0, stream>>>(lens, whh_w, b_hh, gates, hfin);
  logits_mfma<<<dim3((NV + 63) / 64), dim3(512), 0, stream>>>(hfin, emb, out);
}